// Round 1
// baseline (1855.031 us; speedup 1.0000x reference)
//
#include <hip/hip_runtime.h>
#include <hip/hip_bf16.h>

#define HW 112
#define HWHW 12544           // 112*112
#define NB 32                // batch
#define CIN 64               // total input channels
#define G 4
#define IN_G 16
#define OUT_G 32

// ---------- float <-> ordered uint encoding for atomic min/max ----------
__device__ __forceinline__ unsigned enc_f32(float f) {
    unsigned u = __float_as_uint(f);
    return (u & 0x80000000u) ? ~u : (u | 0x80000000u);
}
__device__ __forceinline__ float dec_f32(unsigned k) {
    unsigned u = (k & 0x80000000u) ? (k & 0x7fffffffu) : ~k;
    return __uint_as_float(u);
}

// ---------- init workspace min/max slots ----------
__global__ void init_mm(unsigned* mm) {
    int i = threadIdx.x;
    if (i < 2 * G) mm[i] = (i & 1) ? 0u : 0xFFFFFFFFu;  // even=min slot, odd=max slot
}

// ---------- per-group global min/max ----------
__global__ __launch_bounds__(256) void minmax_kernel(const float* __restrict__ x,
                                                     unsigned* __restrict__ mm) {
    const int g = blockIdx.y;
    const int chunk = IN_G * HWHW;                 // 200704 floats per batch per group
    const int group_elems = NB * chunk;            // 6422528
    float lmin = 3.4e38f, lmax = -3.4e38f;
    int stride = gridDim.x * blockDim.x * 4;
    for (int i = (blockIdx.x * blockDim.x + threadIdx.x) * 4; i < group_elems; i += stride) {
        int n = i / chunk;
        int r = i - n * chunk;
        const float4 v = *(const float4*)(x + ((long long)n * CIN + g * IN_G) * HWHW + r);
        lmin = fminf(lmin, fminf(fminf(v.x, v.y), fminf(v.z, v.w)));
        lmax = fmaxf(lmax, fmaxf(fmaxf(v.x, v.y), fmaxf(v.z, v.w)));
    }
    // wave reduce (64 lanes)
    for (int o = 32; o > 0; o >>= 1) {
        lmin = fminf(lmin, __shfl_down(lmin, o));
        lmax = fmaxf(lmax, __shfl_down(lmax, o));
    }
    __shared__ float smn[4], smx[4];
    int wid = threadIdx.x >> 6, lane = threadIdx.x & 63;
    if (lane == 0) { smn[wid] = lmin; smx[wid] = lmax; }
    __syncthreads();
    if (threadIdx.x == 0) {
        float m0 = fminf(fminf(smn[0], smn[1]), fminf(smn[2], smn[3]));
        float m1 = fmaxf(fmaxf(smx[0], smx[1]), fmaxf(smx[2], smx[3]));
        atomicMin(&mm[2 * g],     enc_f32(m0));
        atomicMax(&mm[2 * g + 1], enc_f32(m1));
    }
}

// ---------- fused base-conv + legendre-poly-conv ----------
// grid: (49 tiles, 4 groups, 32 batch); block: 256 = 16x16 output pixels
// each thread accumulates all 32 output channels for its pixel.
__global__ __launch_bounds__(256) void conv_kernel(const float* __restrict__ x,
                                                   const float* __restrict__ bw,
                                                   const float* __restrict__ pw,
                                                   const unsigned* __restrict__ mm,
                                                   float* __restrict__ out) {
    const int tileIdx = blockIdx.x;          // 0..48 (7x7)
    const int g = blockIdx.y;
    const int n = blockIdx.z;
    const int ty0 = (tileIdx / 7) * 16;
    const int tx0 = (tileIdx % 7) * 16;

    __shared__ float sb[5][18][18];          // p0, x, xn, P2, P3 (zero-padded halo)

    const float mn = dec_f32(mm[2 * g]);
    const float mx = dec_f32(mm[2 * g + 1]);
    const float a = 2.0f / (mx - mn);
    const float b = -a * mn - 1.0f;

    const int tid = threadIdx.x;
    const int ty = tid >> 4, tx = tid & 15;

    float acc[OUT_G];
#pragma unroll
    for (int i = 0; i < OUT_G; ++i) acc[i] = 0.0f;

    const float* xg = x + ((long long)n * CIN + g * IN_G) * HWHW;
    const float* bwg = bw + (long long)(g * OUT_G * IN_G) * 9;            // [co][ci][9], co stride 144
    const float* pwg = pw + (long long)(g * OUT_G * IN_G * 4) * 9;        // [co][d*16+ci][9], co stride 576

    for (int ci = 0; ci < IN_G; ++ci) {
        __syncthreads();
        for (int l = tid; l < 18 * 18; l += 256) {
            int ly = l / 18, lx = l - ly * 18;
            int gy = ty0 + ly - 1, gx = tx0 + lx - 1;
            bool ok = (gy >= 0) && (gy < HW) && (gx >= 0) && (gx < HW);
            float xv = ok ? xg[ci * HWHW + gy * HW + gx] : 0.0f;
            float p0 = ok ? 1.0f : 0.0f;
            float xn = ok ? (a * xv + b) : 0.0f;
            float p2 = 1.5f * xn * xn - 0.5f * p0;
            float p3 = 2.5f * xn * xn * xn - 1.5f * xn;
            sb[0][ly][lx] = p0;
            sb[1][ly][lx] = xv;
            sb[2][ly][lx] = xn;
            sb[3][ly][lx] = p2;
            sb[4][ly][lx] = p3;
        }
        __syncthreads();

        const float* bwp = bwg + ci * 9;
        const float* pwp = pwg + ci * 9;
#pragma unroll
        for (int kh = 0; kh < 3; ++kh) {
#pragma unroll
            for (int kw = 0; kw < 3; ++kw) {
                const int tap = kh * 3 + kw;
                const float v0 = sb[0][ty + kh][tx + kw];
                const float vx = sb[1][ty + kh][tx + kw];
                const float vn = sb[2][ty + kh][tx + kw];
                const float v2 = sb[3][ty + kh][tx + kw];
                const float v3 = sb[4][ty + kh][tx + kw];
#pragma unroll
                for (int co = 0; co < OUT_G; ++co) {
                    float s = acc[co];
                    s += bwp[co * 144 + tap] * vx;
                    s += pwp[co * 576 + tap] * v0;
                    s += pwp[co * 576 + 144 + tap] * vn;
                    s += pwp[co * 576 + 288 + tap] * v2;
                    s += pwp[co * 576 + 432 + tap] * v3;
                    acc[co] = s;
                }
            }
        }
    }

    const long long obase = ((long long)n * (G * OUT_G) + g * OUT_G) * HWHW
                          + (ty0 + ty) * HW + (tx0 + tx);
#pragma unroll
    for (int co = 0; co < OUT_G; ++co) out[obase + (long long)co * HWHW] = acc[co];
}

// ---------- per-(n,c) instance norm + SiLU, in place on out ----------
__global__ __launch_bounds__(256) void norm_kernel(float* __restrict__ out) {
    __shared__ float buf[HWHW];              // 50176 B
    __shared__ float red[2][4];
    const long long nc = blockIdx.x;         // 0..4095
    float* p = out + nc * HWHW;

    float s = 0.0f, ss = 0.0f;
    for (int i = threadIdx.x; i < HWHW / 4; i += 256) {
        float4 v = ((const float4*)p)[i];
        ((float4*)buf)[i] = v;
        s += v.x + v.y + v.z + v.w;
        ss += v.x * v.x + v.y * v.y + v.z * v.z + v.w * v.w;
    }
    for (int o = 32; o > 0; o >>= 1) {
        s  += __shfl_down(s, o);
        ss += __shfl_down(ss, o);
    }
    const int wid = threadIdx.x >> 6, lane = threadIdx.x & 63;
    if (lane == 0) { red[0][wid] = s; red[1][wid] = ss; }
    __syncthreads();
    if (threadIdx.x == 0) {
        float S  = red[0][0] + red[0][1] + red[0][2] + red[0][3];
        float SS = red[1][0] + red[1][1] + red[1][2] + red[1][3];
        float mu = S * (1.0f / HWHW);
        float var = SS * (1.0f / HWHW) - mu * mu;
        red[0][0] = mu;
        red[1][0] = rsqrtf(var + 1e-5f);
    }
    __syncthreads();
    const float mu = red[0][0], rs = red[1][0];
    for (int i = threadIdx.x; i < HWHW / 4; i += 256) {
        float4 v = ((float4*)buf)[i];
        v.x = (v.x - mu) * rs; v.x = v.x / (1.0f + __expf(-v.x));
        v.y = (v.y - mu) * rs; v.y = v.y / (1.0f + __expf(-v.y));
        v.z = (v.z - mu) * rs; v.z = v.z / (1.0f + __expf(-v.z));
        v.w = (v.w - mu) * rs; v.w = v.w / (1.0f + __expf(-v.w));
        ((float4*)p)[i] = v;
    }
}

extern "C" void kernel_launch(void* const* d_in, const int* in_sizes, int n_in,
                              void* d_out, int out_size, void* d_ws, size_t ws_size,
                              hipStream_t stream) {
    const float* x  = (const float*)d_in[0];
    const float* bw = (const float*)d_in[1];
    const float* pw = (const float*)d_in[2];
    float* out = (float*)d_out;
    unsigned* mm = (unsigned*)d_ws;

    init_mm<<<1, 64, 0, stream>>>(mm);
    minmax_kernel<<<dim3(256, G), 256, 0, stream>>>(x, mm);
    conv_kernel<<<dim3(49, G, NB), 256, 0, stream>>>(x, bw, pw, mm, out);
    norm_kernel<<<NB * G * OUT_G, 256, 0, stream>>>(out);
}

// Round 2
// 492.353 us; speedup vs baseline: 3.7677x; 3.7677x over previous
//
#include <hip/hip_runtime.h>
#include <hip/hip_bf16.h>

#define HW 112
#define HWHW 12544           // 112*112
#define NB 32                // batch
#define CIN 64               // total input channels
#define G 4
#define IN_G 16
#define OUT_G 32

typedef _Float16 f16;
typedef _Float16 f16x8 __attribute__((ext_vector_type(8)));
typedef _Float16 f16x4 __attribute__((ext_vector_type(4)));
typedef float f32x4 __attribute__((ext_vector_type(4)));

// ---------- float <-> ordered uint encoding for atomic min/max ----------
__device__ __forceinline__ unsigned enc_f32(float f) {
    unsigned u = __float_as_uint(f);
    return (u & 0x80000000u) ? ~u : (u | 0x80000000u);
}
__device__ __forceinline__ float dec_f32(unsigned k) {
    unsigned u = (k & 0x80000000u) ? (k & 0x7fffffffu) : ~k;
    return __uint_as_float(u);
}

__global__ void init_mm(unsigned* mm) {
    int i = threadIdx.x;
    if (i < 2 * G) mm[i] = (i & 1) ? 0u : 0xFFFFFFFFu;
}

__global__ __launch_bounds__(256) void minmax_kernel(const float* __restrict__ x,
                                                     unsigned* __restrict__ mm) {
    const int g = blockIdx.y;
    const int chunk = IN_G * HWHW;
    const int group_elems = NB * chunk;
    float lmin = 3.4e38f, lmax = -3.4e38f;
    int stride = gridDim.x * blockDim.x * 4;
    for (int i = (blockIdx.x * blockDim.x + threadIdx.x) * 4; i < group_elems; i += stride) {
        int n = i / chunk;
        int r = i - n * chunk;
        const float4 v = *(const float4*)(x + ((long long)n * CIN + g * IN_G) * HWHW + r);
        lmin = fminf(lmin, fminf(fminf(v.x, v.y), fminf(v.z, v.w)));
        lmax = fmaxf(lmax, fmaxf(fmaxf(v.x, v.y), fmaxf(v.z, v.w)));
    }
    for (int o = 32; o > 0; o >>= 1) {
        lmin = fminf(lmin, __shfl_down(lmin, o));
        lmax = fmaxf(lmax, __shfl_down(lmax, o));
    }
    __shared__ float smn[4], smx[4];
    int wid = threadIdx.x >> 6, lane = threadIdx.x & 63;
    if (lane == 0) { smn[wid] = lmin; smx[wid] = lmax; }
    __syncthreads();
    if (threadIdx.x == 0) {
        float m0 = fminf(fminf(smn[0], smn[1]), fminf(smn[2], smn[3]));
        float m1 = fmaxf(fmaxf(smx[0], smx[1]), fmaxf(smx[2], smx[3]));
        atomicMin(&mm[2 * g],     enc_f32(m0));
        atomicMax(&mm[2 * g + 1], enc_f32(m1));
    }
}

// ---------- fold base+poly weights into powers-of-x basis, f16, pre-swizzled ----------
// Wf layout: [(g*9+tap)*32 + co] rows of 64 f16; within row, 16B unit u holds
// logical unit (u ^ (co&7)); logical k = ci*4 + d  (d = power of x).
__global__ __launch_bounds__(256) void fold_kernel(const float* __restrict__ bw,
                                                   const float* __restrict__ pw,
                                                   const unsigned* __restrict__ mm,
                                                   f16* __restrict__ Wf) {
    int idx = blockIdx.x * 256 + threadIdx.x;           // (g, co, ci, tap)
    if (idx >= G * OUT_G * IN_G * 9) return;
    int g  = idx / (OUT_G * IN_G * 9);
    int r  = idx - g * (OUT_G * IN_G * 9);
    int co = r / (IN_G * 9);
    int r2 = r - co * (IN_G * 9);
    int ci = r2 / 9, tap = r2 - (r2 / 9) * 9;

    const float mn = dec_f32(mm[2 * g]);
    const float mx = dec_f32(mm[2 * g + 1]);
    const float a = 2.0f / (mx - mn);
    const float b = -a * mn - 1.0f;

    const float bwv = bw[((g * OUT_G + co) * IN_G + ci) * 9 + tap];
    const float* pwb = pw + (size_t)(g * OUT_G + co) * 64 * 9;
    const float p0 = pwb[(0  + ci) * 9 + tap];
    const float p1 = pwb[(16 + ci) * 9 + tap];
    const float p2 = pwb[(32 + ci) * 9 + tap];
    const float p3 = pwb[(48 + ci) * 9 + tap];

    // Legendre(xn) with xn = a*x+b expanded in powers of x
    const float W0 = p0 + p1 * b + p2 * (1.5f * b * b - 0.5f) + p3 * (2.5f * b * b * b - 1.5f * b);
    const float W1 = bwv + p1 * a + p2 * (3.0f * a * b) + p3 * (7.5f * a * b * b - 1.5f * a);
    const float W2 = p2 * (1.5f * a * a) + p3 * (7.5f * a * a * b);
    const float W3 = p3 * (2.5f * a * a * a);

    f16x4 v; v[0] = (f16)W0; v[1] = (f16)W1; v[2] = (f16)W2; v[3] = (f16)W3;
    size_t off = ((size_t)((g * 9 + tap) * OUT_G + co)) * 64
               + (size_t)(((ci >> 1) ^ (co & 7)) * 8 + (ci & 1) * 4);
    *(f16x4*)(Wf + off) = v;
}

// ---------- MFMA implicit-GEMM conv ----------
// grid (49, 4, 32), block 256 = 4 waves. Tile 16x16 output px, all 32 co.
// A in LDS: planes-last [18][18][64 f16] zero-padded halo, XOR-swizzled 16B units.
// B (folded weights) per-tap 4KB, double-buffered.
__global__ __launch_bounds__(256) void conv_mfma(const float* __restrict__ x,
                                                 const f16* __restrict__ Wf,
                                                 float* __restrict__ out) {
    const int tile = blockIdx.x, g = blockIdx.y, n = blockIdx.z;
    const int ty0 = (tile / 7) * 16, tx0 = (tile % 7) * 16;

    __shared__ __align__(16) char As[18 * 18 * 128];   // 41472 B
    __shared__ __align__(16) char Ws[2][4096];         // 8192 B

    const int tid = threadIdx.x;
    const float* xg = x + ((size_t)n * CIN + g * IN_G) * HWHW;
    const char* WfG = (const char*)(Wf + (size_t)g * 9 * 2048);

    // stage W for tap 0
    *(uint4*)(&Ws[0][tid * 16]) = *(const uint4*)(WfG + tid * 16);

    // stage A: 324 halo pixels x 8 ci-pairs; each thread packs [1,x,x^2,x^3] for 2 ci
    for (int it = 0; it < 11; ++it) {
        int j = tid + it * 256;
        if (j < 2592) {
            int cip = j / 324, pxIdx = j - cip * 324;
            int py = pxIdx / 18, px = pxIdx - py * 18;
            int gy = ty0 + py - 1, gx = tx0 + px - 1;
            bool ok = (gy >= 0) & (gy < HW) & (gx >= 0) & (gx < HW);
            const float* src = xg + (size_t)(2 * cip) * HWHW + gy * HW + gx;
            float v0 = ok ? src[0] : 0.0f;
            float v1 = ok ? src[HWHW] : 0.0f;
            f16 one = ok ? (f16)1.0f : (f16)0.0f;
            f16x8 pk;
            pk[0] = one; pk[1] = (f16)v0; pk[2] = (f16)(v0 * v0); pk[3] = (f16)(v0 * v0 * v0);
            pk[4] = one; pk[5] = (f16)v1; pk[6] = (f16)(v1 * v1); pk[7] = (f16)(v1 * v1 * v1);
            *(f16x8*)(&As[pxIdx * 128 + ((cip ^ (px & 7)) << 4)]) = pk;
        }
    }
    __syncthreads();

    const int l = tid & 63, w = tid >> 6;
    const int lx = l & 15, qu = l >> 4;

    // per-lane swizzled offsets (compile-time-indexed only)
    int aoff[3][2], boff[2][2];
#pragma unroll
    for (int kw = 0; kw < 3; ++kw)
#pragma unroll
        for (int k2 = 0; k2 < 2; ++k2) {
            int pxr = lx + kw;
            aoff[kw][k2] = pxr * 128 + (((qu + 4 * k2) ^ (pxr & 7)) << 4);
        }
#pragma unroll
    for (int cs = 0; cs < 2; ++cs)
#pragma unroll
        for (int k2 = 0; k2 < 2; ++k2)
            boff[cs][k2] = (lx + 16 * cs) * 128 + (((qu + 4 * k2) ^ (lx & 7)) << 4);

    f32x4 acc[4][2];
#pragma unroll
    for (int rr = 0; rr < 4; ++rr)
#pragma unroll
        for (int cs = 0; cs < 2; ++cs) acc[rr][cs] = (f32x4)0.0f;

#pragma unroll
    for (int tap = 0; tap < 9; ++tap) {
        uint4 wpre;
        if (tap < 8) wpre = *(const uint4*)(WfG + (tap + 1) * 4096 + tid * 16);
        const char* Wb = Ws[tap & 1];
        const int kh = tap / 3, kw = tap - kh * 3;

        f16x8 b00 = *(const f16x8*)(Wb + boff[0][0]);
        f16x8 b10 = *(const f16x8*)(Wb + boff[1][0]);
        f16x8 b01 = *(const f16x8*)(Wb + boff[0][1]);
        f16x8 b11 = *(const f16x8*)(Wb + boff[1][1]);
#pragma unroll
        for (int rr = 0; rr < 4; ++rr) {
            int row = (4 * w + rr + kh) * 2304;
            f16x8 a0 = *(const f16x8*)(As + row + aoff[kw][0]);
            f16x8 a1 = *(const f16x8*)(As + row + aoff[kw][1]);
            acc[rr][0] = __builtin_amdgcn_mfma_f32_16x16x32_f16(a0, b00, acc[rr][0], 0, 0, 0);
            acc[rr][1] = __builtin_amdgcn_mfma_f32_16x16x32_f16(a0, b10, acc[rr][1], 0, 0, 0);
            acc[rr][0] = __builtin_amdgcn_mfma_f32_16x16x32_f16(a1, b01, acc[rr][0], 0, 0, 0);
            acc[rr][1] = __builtin_amdgcn_mfma_f32_16x16x32_f16(a1, b11, acc[rr][1], 0, 0, 0);
        }
        if (tap < 8) *(uint4*)(&Ws[(tap + 1) & 1][tid * 16]) = wpre;
        __syncthreads();
    }

    // epilogue: C lane map (measured): row(M=x) = qu*4+reg, col(N=co) = lx
    const size_t ob = ((size_t)n * (G * OUT_G) + g * OUT_G) * HWHW;
#pragma unroll
    for (int rr = 0; rr < 4; ++rr) {
        const int y = ty0 + 4 * w + rr;
#pragma unroll
        for (int cs = 0; cs < 2; ++cs) {
            float* dst = out + ob + (size_t)(cs * 16 + lx) * HWHW + (size_t)y * HW + tx0 + qu * 4;
            *(f32x4*)dst = acc[rr][cs];
        }
    }
}

// ---------- per-(n,c) instance norm + SiLU, in place ----------
__global__ __launch_bounds__(256) void norm_kernel(float* __restrict__ out) {
    __shared__ float buf[HWHW];
    __shared__ float red[2][4];
    const long long nc = blockIdx.x;
    float* p = out + nc * HWHW;

    float s = 0.0f, ss = 0.0f;
    for (int i = threadIdx.x; i < HWHW / 4; i += 256) {
        float4 v = ((const float4*)p)[i];
        ((float4*)buf)[i] = v;
        s += v.x + v.y + v.z + v.w;
        ss += v.x * v.x + v.y * v.y + v.z * v.z + v.w * v.w;
    }
    for (int o = 32; o > 0; o >>= 1) {
        s  += __shfl_down(s, o);
        ss += __shfl_down(ss, o);
    }
    const int wid = threadIdx.x >> 6, lane = threadIdx.x & 63;
    if (lane == 0) { red[0][wid] = s; red[1][wid] = ss; }
    __syncthreads();
    if (threadIdx.x == 0) {
        float S  = red[0][0] + red[0][1] + red[0][2] + red[0][3];
        float SS = red[1][0] + red[1][1] + red[1][2] + red[1][3];
        float mu = S * (1.0f / HWHW);
        float var = SS * (1.0f / HWHW) - mu * mu;
        red[0][0] = mu;
        red[1][0] = rsqrtf(var + 1e-5f);
    }
    __syncthreads();
    const float mu = red[0][0], rs = red[1][0];
    for (int i = threadIdx.x; i < HWHW / 4; i += 256) {
        float4 v = ((float4*)buf)[i];
        v.x = (v.x - mu) * rs; v.x = v.x / (1.0f + __expf(-v.x));
        v.y = (v.y - mu) * rs; v.y = v.y / (1.0f + __expf(-v.y));
        v.z = (v.z - mu) * rs; v.z = v.z / (1.0f + __expf(-v.z));
        v.w = (v.w - mu) * rs; v.w = v.w / (1.0f + __expf(-v.w));
        ((float4*)p)[i] = v;
    }
}

extern "C" void kernel_launch(void* const* d_in, const int* in_sizes, int n_in,
                              void* d_out, int out_size, void* d_ws, size_t ws_size,
                              hipStream_t stream) {
    const float* x  = (const float*)d_in[0];
    const float* bw = (const float*)d_in[1];
    const float* pw = (const float*)d_in[2];
    float* out = (float*)d_out;
    unsigned* mm = (unsigned*)d_ws;
    f16* Wf = (f16*)((char*)d_ws + 1024);   // 4*9*32*64 f16 = 147456 B

    init_mm<<<1, 64, 0, stream>>>(mm);
    minmax_kernel<<<dim3(256, G), 256, 0, stream>>>(x, mm);
    fold_kernel<<<72, 256, 0, stream>>>(bw, pw, mm, Wf);
    conv_mfma<<<dim3(49, G, NB), 256, 0, stream>>>(x, Wf, out);
    norm_kernel<<<NB * G * OUT_G, 256, 0, stream>>>(out);
}